// Round 1
// 160.459 us; speedup vs baseline: 1.0094x; 1.0094x over previous
//
#include <hip/hip_runtime.h>
#include <math.h>

// (N,C,D,H,W)=(2,32,48,48,48), K=3, T=8. All fp32 in/out (verified R5).
// R11 = R10 + (a) f16 MFMA path: tokens/B in fp16 instead of bf16, so token
// packing is 4x v_cvt_pkrtz (1 op) instead of 16x hand-rolled RNE bf16
// (~8.5 ops each) -> saves ~990 VALU ops/thread (~11%); f16 also has 3 more
// mantissa bits than bf16 -> absmax should improve. (b) B-fragment (bt)
// loads software-pipelined one group ahead so the ~200cy L2 round-trip hides
// under the trilinear section. Theory: grid (864 blocks) is fully co-resident
// in one fill (3.375 blk/CU of 4 capacity), so runtime == per-block critical
// path; VALU (31% busy) is the largest pipe on that path.
#define NB   2
#define CH   32
#define DHW  (48*48*48)
#define TT   8
#define EPSF 1e-6f

#define TILE_N   1521            // 13*13*9 halo tile (voxel words; 1 word = 2 ch fp16)
#define TILE_WSTR 1522           // words per plane (+1 pad)
#define GROUPS   8               // 32 ch / 4 per group (= 2 pair-planes)

// LDS layout (bytes): tokens [0,20480) = 256*80 ; tile pairs [20480,32656)
// cbuf aliases [0,36864) = 256 rows * 36 floats (used only after final barrier)
#define TOK_OFF  0
#define TOK_STR  80              // 64B tokens + 16B pad
#define TILE_OFF 20480
#define SMEM_SZ  36864

// ws layout (float idx): Bt f16 [0,4096) floats (=8192 ushort), wf 4096, bf 4480, bm 4492
#define WS_BT_F 0
#define WS_WF   4096
#define WS_BF   4480
#define WS_BM   4492

typedef __attribute__((ext_vector_type(8))) short short8;
typedef __attribute__((ext_vector_type(8))) _Float16 half8;
typedef __attribute__((ext_vector_type(4))) float floatx4;
typedef __attribute__((ext_vector_type(2))) _Float16 h2;

__device__ __forceinline__ h2 pkrtz(float a, float b) {
    return __builtin_bit_cast(h2, __builtin_amdgcn_cvt_pkrtz(a, b));
}
__device__ __forceinline__ unsigned pkrtz_u(float a, float b) {
    return __builtin_bit_cast(unsigned, __builtin_amdgcn_cvt_pkrtz(a, b));
}

__global__ __launch_bounds__(256) void prep_kernel(
        const float* __restrict__ w_field,
        const float* __restrict__ b_field,
        const float* __restrict__ gates,
        const float* __restrict__ w_mix,
        const float* __restrict__ b_mix,
        float* __restrict__ ws) {
    int i = blockIdx.x * 256 + threadIdx.x;    // grid 32*256 = 8192
    // Bt[o][k] f16 (RNE), k = c*8 + t, value = sigmoid(gates[t]) * w_mix[o, t*32+c]
    {
        int o = i >> 8, k = i & 255, c = k >> 3, t = k & 7;
        float sg = 1.0f / (1.0f + expf(-gates[t]));
        _Float16 hv = (_Float16)(sg * w_mix[o * 256 + t * 32 + c]);
        ((unsigned short*)(ws + WS_BT_F))[o * 256 + k] = __builtin_bit_cast(unsigned short, hv);
    }
    if (i < 384) { int c = i / 12, o = i - c * 12; ws[WS_WF + i] = w_field[o * 32 + c]; }
    if (i < 12)  ws[WS_BF + i] = b_field[i];
    if (i < 32)  ws[WS_BM + i] = b_mix[i];
}

__global__ __launch_bounds__(256) void geo_main(
        const float* __restrict__ x,
        const float* __restrict__ ws,
        float* __restrict__ out) {
    __shared__ __align__(16) char smem[SMEM_SZ];
    char* tokb  = smem + TOK_OFF;
    h2*   tileP = (h2*)(smem + TILE_OFF);      // word-indexed, 2 planes of TILE_WSTR
    float* cbuf = (float*)smem;                // alias, post-loop only

    const int tid = threadIdx.x;
    // XCD-locality swizzle: chunk c = blockIdx&7 (presumed XCD via round-robin
    // dispatch) gets lin in [108c, 108(c+1)) -> one batch, 3 contiguous z-slabs.
    const int lin = (blockIdx.x & 7) * 108 + (blockIdx.x >> 3);
    const int bx = lin % 6, by = (lin / 6) % 6, bz = (lin / 36) % 12, n = lin / 432;
    const int lx = tid & 7, ly = (tid >> 3) & 7, lz = tid >> 6;
    const int w = bx * 8 + lx, h = by * 8 + ly, d = bz * 4 + lz;
    const int xlo = bx * 8 - 2, ylo = by * 8 - 2, zlo = bz * 4 - 2;
    const int lane = tid & 63, w64 = tid & 192;

    const float* xn = x + (size_t)n * CH * DHW;

    // ---- channel-invariant halo-load offsets ----
    int goff[6];
#pragma unroll
    for (int i = 0; i < 6; ++i) {
        int e  = tid + i * 256;
        int ee = (e < TILE_N) ? e : 0;
        int tz = ee / 169; int r0 = ee - tz * 169;
        int ty = r0 / 13;  int tx = r0 - ty * 13;
        int zg = min(max(zlo + tz, 0), 47);
        int yg = min(max(ylo + ty, 0), 47);
        int xg = min(max(xlo + tx, 0), 47);
        goff[i] = (zg * 48 + yg) * 48 + xg;
    }

    // ---- phase A: f[12] = w_field @ x(:,pos) + b_field ----
    const int pos = (d * 48 + h) * 48 + w;
    float f[12];
#pragma unroll
    for (int o = 0; o < 12; ++o) f[o] = ws[WS_BF + o];
    for (int c = 0; c < CH; ++c) {
        float xv = xn[c * DHW + pos];
        const float* wf = ws + WS_WF + c * 12;
#pragma unroll
        for (int o = 0; o < 12; ++o) f[o] = fmaf(wf[o], xv, f[o]);
    }

    // ---- per-voxel sample parameters ----
    h2 fx2[6], fy2[6], fz2[6];
    int a00[6], a01[6], a10[6], a11[6];
    float uxk[3], uyk[3], uzk[3], irk[3], ir2k[3];
    const float cscale = 48.0f / (48.0f + EPSF);
#pragma unroll
    for (int k = 0; k < 3; ++k) {
        float vx = f[4*k], vy = f[4*k+1], vz = f[4*k+2], s = f[4*k+3];
        float inv = 1.0f / sqrtf(vx*vx + vy*vy + vz*vz + EPSF);
        float ux = vx * inv, uy = vy * inv, uz = vz * inv;
        float r  = 0.5f + 1.5f / (1.0f + expf(-s));
        uxk[k] = ux; uyk[k] = uy; uzk[k] = uz;
        float ir = 1.0f / (r + EPSF); irk[k] = ir; ir2k[k] = ir * ir;
#pragma unroll
        for (int sgn = 0; sgn < 2; ++sgn) {
            int   si = 2 * k + sgn;
            float sf = sgn ? -1.0f : 1.0f;
            float txr = (float)w + sf * r * ux * cscale;
            float tyr = (float)h + sf * r * uy * cscale;
            float tzr = (float)d + sf * r * uz * cscale;
            float cx = fabsf(txr + 0.5f); float ix = fminf(cx, 96.0f - cx) - 0.5f;
            float cy = fabsf(tyr + 0.5f); float iy = fminf(cy, 96.0f - cy) - 0.5f;
            float cz = fabsf(tzr + 0.5f); float iz = fminf(cz, 96.0f - cz) - 0.5f;
            float x0f = floorf(ix), y0f = floorf(iy), z0f = floorf(iz);
            float fx = ix - x0f, fy = iy - y0f, fz = iz - z0f;
            int x0 = min(max((int)x0f, 0), 47); int x1 = min(x0 + 1, 47);
            int y0 = min(max((int)y0f, 0), 47); int y1 = min(y0 + 1, 47);
            int z0 = min(max((int)z0f, 0), 47); int z1 = min(z0 + 1, 47);
            float fxe = (x1 == x0) ? 0.0f : fx;  // reference's clipped-x1 semantics
            _Float16 hx = (_Float16)fxe, hy = (_Float16)fy, hz = (_Float16)fz;
            fx2[si] = (h2){hx, hx}; fy2[si] = (h2){hy, hy}; fz2[si] = (h2){hz, hz};
            int lz0 = z0 - zlo, lz1 = z1 - zlo;
            int ly0 = y0 - ylo, ly1 = y1 - ylo;
            int lx0 = x0 - xlo;
            a00[si] = (lz0 * 13 + ly0) * 13 + lx0;
            a01[si] = (lz0 * 13 + ly1) * 13 + lx0;
            a10[si] = (lz1 * 13 + ly0) * 13 + lx0;
            a11[si] = (lz1 * 13 + ly1) * 13 + lx0;
        }
    }

    // ---- stage group 0 tiles (2 planes of fp16 pairs) + zero pad words ----
    if (tid == 0) { tileP[TILE_N] = (h2){0, 0}; tileP[TILE_WSTR + TILE_N] = (h2){0, 0}; }
    {
        float ld[24];
#pragma unroll
        for (int cg = 0; cg < 4; ++cg) {
            const float* xc = xn + cg * DHW;
#pragma unroll
            for (int i = 0; i < 6; ++i) ld[cg * 6 + i] = xc[goff[i]];
        }
#pragma unroll
        for (int p = 0; p < 2; ++p)
#pragma unroll
            for (int i = 0; i < 6; ++i) {
                int e = tid + i * 256;
                if (e < TILE_N)
                    tileP[p * TILE_WSTR + e] = pkrtz(ld[(2*p) * 6 + i], ld[(2*p+1) * 6 + i]);
            }
    }
    __syncthreads();

    floatx4 acc[4][2];
#pragma unroll
    for (int mt = 0; mt < 4; ++mt)
#pragma unroll
        for (int nt = 0; nt < 2; ++nt) acc[mt][nt] = (floatx4){0.f, 0.f, 0.f, 0.f};

    const int self = ((lz + 2) * 13 + (ly + 2)) * 13 + (lx + 2);
    const unsigned short* bt = (const unsigned short*)(ws + WS_BT_F);
    const int tokq = (tid >> 3) & 3;           // token-quadrant swizzle key
    const int qm = lane >> 4, nlo = lane & 15;

    // B-fragment pipeline: group 0 loaded before the loop; in-loop we prefetch
    // g+1 at the top so the L2 latency hides under trilinear compute.
    short8 bc0 = *(const short8*)(bt + (nlo * 256 + qm * 8));
    short8 bc1 = *(const short8*)(bt + ((nlo + 16) * 256 + qm * 8));

    for (int g = 0; g < GROUPS; ++g) {
        float nld[24];
        short8 bn0 = bc0, bn1 = bc1;
        if (g < GROUPS - 1) {
            const float* xg = xn + (g + 1) * 4 * DHW;
#pragma unroll
            for (int cg = 0; cg < 4; ++cg) {
                const float* xc = xg + cg * DHW;
#pragma unroll
                for (int i = 0; i < 6; ++i) nld[cg * 6 + i] = xc[goff[i]];
            }
            bn0 = *(const short8*)(bt + (nlo * 256 + (g + 1) * 32 + qm * 8));
            bn1 = *(const short8*)(bt + ((nlo + 16) * 256 + (g + 1) * 32 + qm * 8));
        }
        // ---- packed trilinear: 2 channels per plane, 2 planes ----
#pragma unroll
        for (int p = 0; p < 2; ++p) {
            const h2* tb = tileP + p * TILE_WSTR;
            h2 s2 = tb[self];
            h2 v2[6];
#pragma unroll
            for (int si = 0; si < 6; ++si) {
                int b00 = a00[si], b01 = a01[si], b10 = a10[si], b11 = a11[si];
                h2 v000 = tb[b00], v001 = tb[b00 + 1];
                h2 v010 = tb[b01], v011 = tb[b01 + 1];
                h2 v100 = tb[b10], v101 = tb[b10 + 1];
                h2 v110 = tb[b11], v111 = tb[b11 + 1];
                h2 c00 = v000 + fx2[si] * (v001 - v000);
                h2 c01 = v010 + fx2[si] * (v011 - v010);
                h2 c10 = v100 + fx2[si] * (v101 - v100);
                h2 c11 = v110 + fx2[si] * (v111 - v110);
                h2 c0  = c00 + fy2[si] * (c01 - c00);
                h2 c1  = c10 + fy2[si] * (c11 - c10);
                v2[si] = c0 + fz2[si] * (c1 - c0);
            }
            // ---- per-channel token assembly (fp32 math, fp16 pack) ----
#pragma unroll
            for (int sub = 0; sub < 2; ++sub) {
                float xv = sub ? (float)s2.y : (float)s2.x;
                float val[6];
#pragma unroll
                for (int si = 0; si < 6; ++si)
                    val[si] = sub ? (float)v2[si].y : (float)v2[si].x;
                float t1, t2, t3, gx, gy, gz, l;
                {
                    float sp, sm, d1;
                    sp = val[0]; sm = val[1]; t1 = 0.5f * (sp + sm);
                    d1 = 0.5f * (sp - sm) * irk[0];
                    gx = uxk[0] * d1; gy = uyk[0] * d1; gz = uzk[0] * d1;
                    l  = (sp + sm - 2.0f * xv) * ir2k[0];
                    sp = val[2]; sm = val[3]; t2 = 0.5f * (sp + sm);
                    d1 = 0.5f * (sp - sm) * irk[1];
                    gx = fmaf(uxk[1], d1, gx); gy = fmaf(uyk[1], d1, gy); gz = fmaf(uzk[1], d1, gz);
                    l  = fmaf(sp + sm - 2.0f * xv, ir2k[1], l);
                    sp = val[4]; sm = val[5]; t3 = 0.5f * (sp + sm);
                    d1 = 0.5f * (sp - sm) * irk[2];
                    gx = fmaf(uxk[2], d1, gx); gy = fmaf(uyk[2], d1, gy); gz = fmaf(uzk[2], d1, gz);
                    l  = fmaf(sp + sm - 2.0f * xv, ir2k[2], l);
                }
                uint4 tw;
                tw.x = pkrtz_u(xv, t1);
                tw.y = pkrtz_u(t2, t3);
                tw.z = pkrtz_u(gx, gy);
                tw.w = pkrtz_u(gz, l * (1.0f / 3.0f));
                int cg = 2 * p + sub;
                int qe = cg ^ tokq;            // bank-conflict-free token write
                *(uint4*)(tokb + tid * TOK_STR + qe * 16) = tw;
            }
        }
        __syncthreads();   // tokens visible; tile reads complete

        if (g < GROUPS - 1) {
#pragma unroll
            for (int p = 0; p < 2; ++p)
#pragma unroll
                for (int i = 0; i < 6; ++i) {
                    int e = tid + i * 256;
                    if (e < TILE_N)
                        tileP[p * TILE_WSTR + e] = pkrtz(nld[(2*p) * 6 + i], nld[(2*p+1) * 6 + i]);
                }
        }
        // ---- MFMA: K-chunk g (k = g*32 .. g*32+31), fp16 ----
        {
            half8 hb0 = __builtin_bit_cast(half8, bc0);
            half8 hb1 = __builtin_bit_cast(half8, bc1);
#pragma unroll
            for (int mt = 0; mt < 4; ++mt) {
                int row = w64 + mt * 16 + nlo;
                int qe  = qm ^ ((row >> 3) & 3);
                half8 a = __builtin_bit_cast(half8,
                          *(const short8*)(tokb + row * TOK_STR + qe * 16));
                acc[mt][0] = __builtin_amdgcn_mfma_f32_16x16x32_f16(a, hb0, acc[mt][0], 0, 0, 0);
                acc[mt][1] = __builtin_amdgcn_mfma_f32_16x16x32_f16(a, hb1, acc[mt][1], 0, 0, 0);
            }
        }
        bc0 = bn0; bc1 = bn1;
        __syncthreads();   // tile writes visible; token reads complete
    }

    // ---- C writeback via LDS (col-swizzled, conflict-free) ----
    {
#pragma unroll
        for (int mt = 0; mt < 4; ++mt)
#pragma unroll
            for (int nt = 0; nt < 2; ++nt)
#pragma unroll
                for (int r = 0; r < 4; ++r) {
                    int v = w64 + mt * 16 + qm * 4 + r;
                    int col = nt * 16 + nlo;
                    cbuf[v * 36 + (col ^ (v & 31))] = acc[mt][nt][r];
                }
    }
    __syncthreads();

    // ---- epilogue: out = x + delta + b_mix (coalesced, nontemporal) ----
    const float* dr = cbuf + tid * 36;
    float* on = out + (size_t)n * CH * DHW;
#pragma unroll
    for (int o = 0; o < 32; ++o)
        __builtin_nontemporal_store(
            xn[o * DHW + pos] + dr[o ^ (tid & 31)] + ws[WS_BM + o],
            on + o * DHW + pos);
}

extern "C" void kernel_launch(void* const* d_in, const int* in_sizes, int n_in,
                              void* d_out, int out_size, void* d_ws, size_t ws_size,
                              hipStream_t stream) {
    const float *x = (const float*)d_in[0], *w_field = (const float*)d_in[1],
                *b_field = (const float*)d_in[2], *gates = (const float*)d_in[3],
                *w_mix = (const float*)d_in[4], *b_mix = (const float*)d_in[5];
    for (int i = 0; i < n_in; ++i) {
        switch (in_sizes[i]) {
            case NB * CH * DHW: x       = (const float*)d_in[i]; break;
            case 12 * CH:       w_field = (const float*)d_in[i]; break;
            case 12:            b_field = (const float*)d_in[i]; break;
            case TT:            gates   = (const float*)d_in[i]; break;
            case CH * TT * CH:  w_mix   = (const float*)d_in[i]; break;
            case CH:            b_mix   = (const float*)d_in[i]; break;
            default: break;
        }
    }
    float* ws = (float*)d_ws;
    prep_kernel<<<32, 256, 0, stream>>>(w_field, b_field, gates, w_mix, b_mix, ws);
    geo_main<<<864, 256, 0, stream>>>(x, ws, (float*)d_out);
}

// Round 2
// 160.238 us; speedup vs baseline: 1.0108x; 1.0014x over previous
//
#include <hip/hip_runtime.h>
#include <math.h>

// (N,C,D,H,W)=(2,32,48,48,48), K=3, T=8. All fp32 in/out (verified R5).
// R12 = R11 + single-barrier group loop via double-buffered halo tile.
// Key fact: tokens are WAVE-PRIVATE (thread tid writes row tid; MFMA reads
// rows [w64,w64+64) = own wave) -> token write->MFMA read needs only lgkmcnt,
// no barrier. Only the halo tile is cross-wave. Double-buffering the tile
// (compute from buf, stage g+1 into buf^1) cuts barriers 17 -> 9 and lets
// waves slide across phases. To keep 4 blocks/CU (864 grid = 3.375/CU must
// stay fully co-resident), token stride shrinks 80->64B; the cg^tokq quadrant
// swizzle remains bank-conflict-free at stride 64 for both b128 write (8
// lanes x 8 quads) and MFMA read. LDS = 16384 + 4*1522*4 = 40736 -> 4/CU.
#define NB   2
#define CH   32
#define DHW  (48*48*48)
#define TT   8
#define EPSF 1e-6f

#define TILE_N   1521            // 13*13*9 halo tile (voxel words; 1 word = 2 ch fp16)
#define TILE_WSTR 1522           // words per plane (+1 pad)
#define GROUPS   8               // 32 ch / 4 per group (= 2 pair-planes)

// LDS layout (bytes): tokens [0,16384) = 256*64 ; tile 4 planes [16384,40736)
// cbuf aliases [0,36864) = 256 rows * 36 floats (used only after final barrier)
#define TOK_OFF  0
#define TOK_STR  64              // 64B tokens, quadrant-XOR swizzled
#define TILE_OFF 16384
#define SMEM_SZ  40736

// ws layout (float idx): Bt f16 [0,4096) floats (=8192 ushort), wf 4096, bf 4480, bm 4492
#define WS_BT_F 0
#define WS_WF   4096
#define WS_BF   4480
#define WS_BM   4492

typedef __attribute__((ext_vector_type(8))) short short8;
typedef __attribute__((ext_vector_type(8))) _Float16 half8;
typedef __attribute__((ext_vector_type(4))) float floatx4;
typedef __attribute__((ext_vector_type(2))) _Float16 h2;

__device__ __forceinline__ h2 pkrtz(float a, float b) {
    return __builtin_bit_cast(h2, __builtin_amdgcn_cvt_pkrtz(a, b));
}
__device__ __forceinline__ unsigned pkrtz_u(float a, float b) {
    return __builtin_bit_cast(unsigned, __builtin_amdgcn_cvt_pkrtz(a, b));
}

__global__ __launch_bounds__(256) void prep_kernel(
        const float* __restrict__ w_field,
        const float* __restrict__ b_field,
        const float* __restrict__ gates,
        const float* __restrict__ w_mix,
        const float* __restrict__ b_mix,
        float* __restrict__ ws) {
    int i = blockIdx.x * 256 + threadIdx.x;    // grid 32*256 = 8192
    // Bt[o][k] f16 (RNE), k = c*8 + t, value = sigmoid(gates[t]) * w_mix[o, t*32+c]
    {
        int o = i >> 8, k = i & 255, c = k >> 3, t = k & 7;
        float sg = 1.0f / (1.0f + expf(-gates[t]));
        _Float16 hv = (_Float16)(sg * w_mix[o * 256 + t * 32 + c]);
        ((unsigned short*)(ws + WS_BT_F))[o * 256 + k] = __builtin_bit_cast(unsigned short, hv);
    }
    if (i < 384) { int c = i / 12, o = i - c * 12; ws[WS_WF + i] = w_field[o * 32 + c]; }
    if (i < 12)  ws[WS_BF + i] = b_field[i];
    if (i < 32)  ws[WS_BM + i] = b_mix[i];
}

__global__ __launch_bounds__(256) void geo_main(
        const float* __restrict__ x,
        const float* __restrict__ ws,
        float* __restrict__ out) {
    __shared__ __align__(16) char smem[SMEM_SZ];
    char* tokb  = smem + TOK_OFF;
    h2*   tileP = (h2*)(smem + TILE_OFF);      // word-indexed, 4 planes of TILE_WSTR
    float* cbuf = (float*)smem;                // alias, post-loop only

    const int tid = threadIdx.x;
    // XCD-locality swizzle: chunk c = blockIdx&7 (presumed XCD via round-robin
    // dispatch) gets lin in [108c, 108(c+1)) -> one batch, 3 contiguous z-slabs.
    const int lin = (blockIdx.x & 7) * 108 + (blockIdx.x >> 3);
    const int bx = lin % 6, by = (lin / 6) % 6, bz = (lin / 36) % 12, n = lin / 432;
    const int lx = tid & 7, ly = (tid >> 3) & 7, lz = tid >> 6;
    const int w = bx * 8 + lx, h = by * 8 + ly, d = bz * 4 + lz;
    const int xlo = bx * 8 - 2, ylo = by * 8 - 2, zlo = bz * 4 - 2;
    const int lane = tid & 63, w64 = tid & 192;

    const float* xn = x + (size_t)n * CH * DHW;

    // ---- channel-invariant halo-load offsets ----
    int goff[6];
#pragma unroll
    for (int i = 0; i < 6; ++i) {
        int e  = tid + i * 256;
        int ee = (e < TILE_N) ? e : 0;
        int tz = ee / 169; int r0 = ee - tz * 169;
        int ty = r0 / 13;  int tx = r0 - ty * 13;
        int zg = min(max(zlo + tz, 0), 47);
        int yg = min(max(ylo + ty, 0), 47);
        int xg = min(max(xlo + tx, 0), 47);
        goff[i] = (zg * 48 + yg) * 48 + xg;
    }

    // ---- phase A: f[12] = w_field @ x(:,pos) + b_field ----
    const int pos = (d * 48 + h) * 48 + w;
    float f[12];
#pragma unroll
    for (int o = 0; o < 12; ++o) f[o] = ws[WS_BF + o];
    for (int c = 0; c < CH; ++c) {
        float xv = xn[c * DHW + pos];
        const float* wf = ws + WS_WF + c * 12;
#pragma unroll
        for (int o = 0; o < 12; ++o) f[o] = fmaf(wf[o], xv, f[o]);
    }

    // ---- per-voxel sample parameters ----
    h2 fx2[6], fy2[6], fz2[6];
    int a00[6], a01[6], a10[6], a11[6];
    float uxk[3], uyk[3], uzk[3], irk[3], ir2k[3];
    const float cscale = 48.0f / (48.0f + EPSF);
#pragma unroll
    for (int k = 0; k < 3; ++k) {
        float vx = f[4*k], vy = f[4*k+1], vz = f[4*k+2], s = f[4*k+3];
        float inv = 1.0f / sqrtf(vx*vx + vy*vy + vz*vz + EPSF);
        float ux = vx * inv, uy = vy * inv, uz = vz * inv;
        float r  = 0.5f + 1.5f / (1.0f + expf(-s));
        uxk[k] = ux; uyk[k] = uy; uzk[k] = uz;
        float ir = 1.0f / (r + EPSF); irk[k] = ir; ir2k[k] = ir * ir;
#pragma unroll
        for (int sgn = 0; sgn < 2; ++sgn) {
            int   si = 2 * k + sgn;
            float sf = sgn ? -1.0f : 1.0f;
            float txr = (float)w + sf * r * ux * cscale;
            float tyr = (float)h + sf * r * uy * cscale;
            float tzr = (float)d + sf * r * uz * cscale;
            float cx = fabsf(txr + 0.5f); float ix = fminf(cx, 96.0f - cx) - 0.5f;
            float cy = fabsf(tyr + 0.5f); float iy = fminf(cy, 96.0f - cy) - 0.5f;
            float cz = fabsf(tzr + 0.5f); float iz = fminf(cz, 96.0f - cz) - 0.5f;
            float x0f = floorf(ix), y0f = floorf(iy), z0f = floorf(iz);
            float fx = ix - x0f, fy = iy - y0f, fz = iz - z0f;
            int x0 = min(max((int)x0f, 0), 47); int x1 = min(x0 + 1, 47);
            int y0 = min(max((int)y0f, 0), 47); int y1 = min(y0 + 1, 47);
            int z0 = min(max((int)z0f, 0), 47); int z1 = min(z0 + 1, 47);
            float fxe = (x1 == x0) ? 0.0f : fx;  // reference's clipped-x1 semantics
            _Float16 hx = (_Float16)fxe, hy = (_Float16)fy, hz = (_Float16)fz;
            fx2[si] = (h2){hx, hx}; fy2[si] = (h2){hy, hy}; fz2[si] = (h2){hz, hz};
            int lz0 = z0 - zlo, lz1 = z1 - zlo;
            int ly0 = y0 - ylo, ly1 = y1 - ylo;
            int lx0 = x0 - xlo;
            a00[si] = (lz0 * 13 + ly0) * 13 + lx0;
            a01[si] = (lz0 * 13 + ly1) * 13 + lx0;
            a10[si] = (lz1 * 13 + ly0) * 13 + lx0;
            a11[si] = (lz1 * 13 + ly1) * 13 + lx0;
        }
    }

    // ---- stage group 0 tiles into buffer 0 + zero all 4 pad words ----
    if (tid == 0) {
#pragma unroll
        for (int p = 0; p < 4; ++p) tileP[p * TILE_WSTR + TILE_N] = (h2){0, 0};
    }
    {
        float ld[24];
#pragma unroll
        for (int cg = 0; cg < 4; ++cg) {
            const float* xc = xn + cg * DHW;
#pragma unroll
            for (int i = 0; i < 6; ++i) ld[cg * 6 + i] = xc[goff[i]];
        }
#pragma unroll
        for (int p = 0; p < 2; ++p)
#pragma unroll
            for (int i = 0; i < 6; ++i) {
                int e = tid + i * 256;
                if (e < TILE_N)
                    tileP[p * TILE_WSTR + e] = pkrtz(ld[(2*p) * 6 + i], ld[(2*p+1) * 6 + i]);
            }
    }
    __syncthreads();

    floatx4 acc[4][2];
#pragma unroll
    for (int mt = 0; mt < 4; ++mt)
#pragma unroll
        for (int nt = 0; nt < 2; ++nt) acc[mt][nt] = (floatx4){0.f, 0.f, 0.f, 0.f};

    const int self = ((lz + 2) * 13 + (ly + 2)) * 13 + (lx + 2);
    const unsigned short* bt = (const unsigned short*)(ws + WS_BT_F);
    const int tokq = (tid >> 3) & 3;           // token-quadrant swizzle key
    const int qm = lane >> 4, nlo = lane & 15;

    // B-fragment pipeline: group 0 loaded before the loop; in-loop we prefetch
    // g+1 at the top so the L2 latency hides under trilinear compute.
    short8 bc0 = *(const short8*)(bt + (nlo * 256 + qm * 8));
    short8 bc1 = *(const short8*)(bt + ((nlo + 16) * 256 + qm * 8));

    for (int g = 0; g < GROUPS; ++g) {
        const int rb = (g & 1) * 2;            // read-buffer plane base
        const int wb = 2 - rb;                 // write-buffer plane base
        float nld[24];
        short8 bn0 = bc0, bn1 = bc1;
        if (g < GROUPS - 1) {
            const float* xg = xn + (g + 1) * 4 * DHW;
#pragma unroll
            for (int cg = 0; cg < 4; ++cg) {
                const float* xc = xg + cg * DHW;
#pragma unroll
                for (int i = 0; i < 6; ++i) nld[cg * 6 + i] = xc[goff[i]];
            }
            bn0 = *(const short8*)(bt + (nlo * 256 + (g + 1) * 32 + qm * 8));
            bn1 = *(const short8*)(bt + ((nlo + 16) * 256 + (g + 1) * 32 + qm * 8));
        }
        // ---- packed trilinear: 2 channels per plane, 2 planes ----
#pragma unroll
        for (int p = 0; p < 2; ++p) {
            const h2* tb = tileP + (rb + p) * TILE_WSTR;
            h2 s2 = tb[self];
            h2 v2[6];
#pragma unroll
            for (int si = 0; si < 6; ++si) {
                int b00 = a00[si], b01 = a01[si], b10 = a10[si], b11 = a11[si];
                h2 v000 = tb[b00], v001 = tb[b00 + 1];
                h2 v010 = tb[b01], v011 = tb[b01 + 1];
                h2 v100 = tb[b10], v101 = tb[b10 + 1];
                h2 v110 = tb[b11], v111 = tb[b11 + 1];
                h2 c00 = v000 + fx2[si] * (v001 - v000);
                h2 c01 = v010 + fx2[si] * (v011 - v010);
                h2 c10 = v100 + fx2[si] * (v101 - v100);
                h2 c11 = v110 + fx2[si] * (v111 - v110);
                h2 c0  = c00 + fy2[si] * (c01 - c00);
                h2 c1  = c10 + fy2[si] * (c11 - c10);
                v2[si] = c0 + fz2[si] * (c1 - c0);
            }
            // ---- per-channel token assembly (fp32 math, fp16 pack) ----
#pragma unroll
            for (int sub = 0; sub < 2; ++sub) {
                float xv = sub ? (float)s2.y : (float)s2.x;
                float val[6];
#pragma unroll
                for (int si = 0; si < 6; ++si)
                    val[si] = sub ? (float)v2[si].y : (float)v2[si].x;
                float t1, t2, t3, gx, gy, gz, l;
                {
                    float sp, sm, d1;
                    sp = val[0]; sm = val[1]; t1 = 0.5f * (sp + sm);
                    d1 = 0.5f * (sp - sm) * irk[0];
                    gx = uxk[0] * d1; gy = uyk[0] * d1; gz = uzk[0] * d1;
                    l  = (sp + sm - 2.0f * xv) * ir2k[0];
                    sp = val[2]; sm = val[3]; t2 = 0.5f * (sp + sm);
                    d1 = 0.5f * (sp - sm) * irk[1];
                    gx = fmaf(uxk[1], d1, gx); gy = fmaf(uyk[1], d1, gy); gz = fmaf(uzk[1], d1, gz);
                    l  = fmaf(sp + sm - 2.0f * xv, ir2k[1], l);
                    sp = val[4]; sm = val[5]; t3 = 0.5f * (sp + sm);
                    d1 = 0.5f * (sp - sm) * irk[2];
                    gx = fmaf(uxk[2], d1, gx); gy = fmaf(uyk[2], d1, gy); gz = fmaf(uzk[2], d1, gz);
                    l  = fmaf(sp + sm - 2.0f * xv, ir2k[2], l);
                }
                uint4 tw;
                tw.x = pkrtz_u(xv, t1);
                tw.y = pkrtz_u(t2, t3);
                tw.z = pkrtz_u(gx, gy);
                tw.w = pkrtz_u(gz, l * (1.0f / 3.0f));
                int cg = 2 * p + sub;
                int qe = cg ^ tokq;            // bank-conflict-free token write
                *(uint4*)(tokb + tid * TOK_STR + qe * 16) = tw;
            }
        }
        // ---- MFMA: K-chunk g (k = g*32 .. g*32+31), fp16 ----
        // Tokens are wave-private: lgkmcnt (compiler-inserted) suffices, no barrier.
        {
            half8 hb0 = __builtin_bit_cast(half8, bc0);
            half8 hb1 = __builtin_bit_cast(half8, bc1);
#pragma unroll
            for (int mt = 0; mt < 4; ++mt) {
                int row = w64 + mt * 16 + nlo;
                int qe  = qm ^ ((row >> 3) & 3);
                half8 a = __builtin_bit_cast(half8,
                          *(const short8*)(tokb + row * TOK_STR + qe * 16));
                acc[mt][0] = __builtin_amdgcn_mfma_f32_16x16x32_f16(a, hb0, acc[mt][0], 0, 0, 0);
                acc[mt][1] = __builtin_amdgcn_mfma_f32_16x16x32_f16(a, hb1, acc[mt][1], 0, 0, 0);
            }
        }
        bc0 = bn0; bc1 = bn1;

        // ---- stage g+1 into the other tile buffer (vmcnt covered by above) ----
        if (g < GROUPS - 1) {
#pragma unroll
            for (int p = 0; p < 2; ++p)
#pragma unroll
                for (int i = 0; i < 6; ++i) {
                    int e = tid + i * 256;
                    if (e < TILE_N)
                        tileP[(wb + p) * TILE_WSTR + e] = pkrtz(nld[(2*p) * 6 + i], nld[(2*p+1) * 6 + i]);
                }
        }
        __syncthreads();   // single rendezvous: buf^1 staged, buf reads done
    }

    // ---- C writeback via LDS (col-swizzled, conflict-free) ----
    {
#pragma unroll
        for (int mt = 0; mt < 4; ++mt)
#pragma unroll
            for (int nt = 0; nt < 2; ++nt)
#pragma unroll
                for (int r = 0; r < 4; ++r) {
                    int v = w64 + mt * 16 + qm * 4 + r;
                    int col = nt * 16 + nlo;
                    cbuf[v * 36 + (col ^ (v & 31))] = acc[mt][nt][r];
                }
    }
    __syncthreads();

    // ---- epilogue: out = x + delta + b_mix (coalesced, nontemporal) ----
    const float* dr = cbuf + tid * 36;
    float* on = out + (size_t)n * CH * DHW;
#pragma unroll
    for (int o = 0; o < 32; ++o)
        __builtin_nontemporal_store(
            xn[o * DHW + pos] + dr[o ^ (tid & 31)] + ws[WS_BM + o],
            on + o * DHW + pos);
}

extern "C" void kernel_launch(void* const* d_in, const int* in_sizes, int n_in,
                              void* d_out, int out_size, void* d_ws, size_t ws_size,
                              hipStream_t stream) {
    const float *x = (const float*)d_in[0], *w_field = (const float*)d_in[1],
                *b_field = (const float*)d_in[2], *gates = (const float*)d_in[3],
                *w_mix = (const float*)d_in[4], *b_mix = (const float*)d_in[5];
    for (int i = 0; i < n_in; ++i) {
        switch (in_sizes[i]) {
            case NB * CH * DHW: x       = (const float*)d_in[i]; break;
            case 12 * CH:       w_field = (const float*)d_in[i]; break;
            case 12:            b_field = (const float*)d_in[i]; break;
            case TT:            gates   = (const float*)d_in[i]; break;
            case CH * TT * CH:  w_mix   = (const float*)d_in[i]; break;
            case CH:            b_mix   = (const float*)d_in[i]; break;
            default: break;
        }
    }
    float* ws = (float*)d_ws;
    prep_kernel<<<32, 256, 0, stream>>>(w_field, b_field, gates, w_mix, b_mix, ws);
    geo_main<<<864, 256, 0, stream>>>(x, ws, (float*)d_out);
}

// Round 3
// 156.956 us; speedup vs baseline: 1.0319x; 1.0209x over previous
//
#include <hip/hip_runtime.h>
#include <math.h>

// (N,C,D,H,W)=(2,32,48,48,48), K=3, T=8. All fp32 in/out (verified R5).
// R13 = R12 + 8B tile entries: 4 channels packed per entry (2x h2), so the
// trilinear pass reads 8x ds_read_b64 per site (x-neighbors adjacent at +8B,
// fusable to ds_read2_b64) instead of 16x ds_read_b32 over two planes.
// LDS read instrs/group: ~98 -> ~49 (or ~25 with read2 fusion); staging
// writes 12 -> 6; address VALU halved. f16 math unchanged (v_pk_* on 2x h2).
// LDS total unchanged: 16384 tokens + 2 x 12176 tile buffers = 40736 -> 4/CU.
// Theory: R12's barrier halving was a no-op (89.5us flat) => limiter is the
// trilinear LDS instruction stream + dependent VALU chains, not rendezvous.
#define NB   2
#define CH   32
#define DHW  (48*48*48)
#define TT   8
#define EPSF 1e-6f

#define TILE_N   1521            // 13*13*9 halo tile entries (1 entry = 4 ch fp16, 8B)
#define TILE_WSTR 1522           // entries per buffer (+1 zero pad)
#define GROUPS   8               // 32 ch / 4 per group (= 1 packed pass)

// LDS layout (bytes): tokens [0,16384) = 256*64 ; tile 2 bufs [16384,40736)
// cbuf aliases [0,36864) = 256 rows * 36 floats (used only after final barrier)
#define TOK_OFF  0
#define TOK_STR  64              // 64B tokens, quadrant-XOR swizzled
#define TILE_OFF 16384
#define SMEM_SZ  40736

// ws layout (float idx): Bt f16 [0,4096) floats (=8192 ushort), wf 4096, bf 4480, bm 4492
#define WS_BT_F 0
#define WS_WF   4096
#define WS_BF   4480
#define WS_BM   4492

typedef __attribute__((ext_vector_type(8))) short short8;
typedef __attribute__((ext_vector_type(8))) _Float16 half8;
typedef __attribute__((ext_vector_type(4))) float floatx4;
typedef __attribute__((ext_vector_type(2))) _Float16 h2;

struct __align__(8) q4 { h2 lo, hi; };   // 4 packed channels (8B, b64-aligned)

__device__ __forceinline__ h2 pkrtz(float a, float b) {
    return __builtin_bit_cast(h2, __builtin_amdgcn_cvt_pkrtz(a, b));
}
__device__ __forceinline__ unsigned pkrtz_u(float a, float b) {
    return __builtin_bit_cast(unsigned, __builtin_amdgcn_cvt_pkrtz(a, b));
}

__global__ __launch_bounds__(256) void prep_kernel(
        const float* __restrict__ w_field,
        const float* __restrict__ b_field,
        const float* __restrict__ gates,
        const float* __restrict__ w_mix,
        const float* __restrict__ b_mix,
        float* __restrict__ ws) {
    int i = blockIdx.x * 256 + threadIdx.x;    // grid 32*256 = 8192
    // Bt[o][k] f16 (RNE), k = c*8 + t, value = sigmoid(gates[t]) * w_mix[o, t*32+c]
    {
        int o = i >> 8, k = i & 255, c = k >> 3, t = k & 7;
        float sg = 1.0f / (1.0f + expf(-gates[t]));
        _Float16 hv = (_Float16)(sg * w_mix[o * 256 + t * 32 + c]);
        ((unsigned short*)(ws + WS_BT_F))[o * 256 + k] = __builtin_bit_cast(unsigned short, hv);
    }
    if (i < 384) { int c = i / 12, o = i - c * 12; ws[WS_WF + i] = w_field[o * 32 + c]; }
    if (i < 12)  ws[WS_BF + i] = b_field[i];
    if (i < 32)  ws[WS_BM + i] = b_mix[i];
}

__global__ __launch_bounds__(256) void geo_main(
        const float* __restrict__ x,
        const float* __restrict__ ws,
        float* __restrict__ out) {
    __shared__ __align__(16) char smem[SMEM_SZ];
    char* tokb  = smem + TOK_OFF;
    q4*   tileq = (q4*)(smem + TILE_OFF);      // entry-indexed, 2 buffers of TILE_WSTR
    float* cbuf = (float*)smem;                // alias, post-loop only

    const int tid = threadIdx.x;
    // XCD-locality swizzle: chunk c = blockIdx&7 (presumed XCD via round-robin
    // dispatch) gets lin in [108c, 108(c+1)) -> one batch, 3 contiguous z-slabs.
    const int lin = (blockIdx.x & 7) * 108 + (blockIdx.x >> 3);
    const int bx = lin % 6, by = (lin / 6) % 6, bz = (lin / 36) % 12, n = lin / 432;
    const int lx = tid & 7, ly = (tid >> 3) & 7, lz = tid >> 6;
    const int w = bx * 8 + lx, h = by * 8 + ly, d = bz * 4 + lz;
    const int xlo = bx * 8 - 2, ylo = by * 8 - 2, zlo = bz * 4 - 2;
    const int lane = tid & 63, w64 = tid & 192;

    const float* xn = x + (size_t)n * CH * DHW;

    // ---- channel-invariant halo-load offsets ----
    int goff[6];
#pragma unroll
    for (int i = 0; i < 6; ++i) {
        int e  = tid + i * 256;
        int ee = (e < TILE_N) ? e : 0;
        int tz = ee / 169; int r0 = ee - tz * 169;
        int ty = r0 / 13;  int tx = r0 - ty * 13;
        int zg = min(max(zlo + tz, 0), 47);
        int yg = min(max(ylo + ty, 0), 47);
        int xg = min(max(xlo + tx, 0), 47);
        goff[i] = (zg * 48 + yg) * 48 + xg;
    }

    // ---- phase A: f[12] = w_field @ x(:,pos) + b_field ----
    const int pos = (d * 48 + h) * 48 + w;
    float f[12];
#pragma unroll
    for (int o = 0; o < 12; ++o) f[o] = ws[WS_BF + o];
    for (int c = 0; c < CH; ++c) {
        float xv = xn[c * DHW + pos];
        const float* wf = ws + WS_WF + c * 12;
#pragma unroll
        for (int o = 0; o < 12; ++o) f[o] = fmaf(wf[o], xv, f[o]);
    }

    // ---- per-voxel sample parameters ----
    h2 fx2[6], fy2[6], fz2[6];
    int a00[6], a01[6], a10[6], a11[6];
    float uxk[3], uyk[3], uzk[3], irk[3], ir2k[3];
    const float cscale = 48.0f / (48.0f + EPSF);
#pragma unroll
    for (int k = 0; k < 3; ++k) {
        float vx = f[4*k], vy = f[4*k+1], vz = f[4*k+2], s = f[4*k+3];
        float inv = 1.0f / sqrtf(vx*vx + vy*vy + vz*vz + EPSF);
        float ux = vx * inv, uy = vy * inv, uz = vz * inv;
        float r  = 0.5f + 1.5f / (1.0f + expf(-s));
        uxk[k] = ux; uyk[k] = uy; uzk[k] = uz;
        float ir = 1.0f / (r + EPSF); irk[k] = ir; ir2k[k] = ir * ir;
#pragma unroll
        for (int sgn = 0; sgn < 2; ++sgn) {
            int   si = 2 * k + sgn;
            float sf = sgn ? -1.0f : 1.0f;
            float txr = (float)w + sf * r * ux * cscale;
            float tyr = (float)h + sf * r * uy * cscale;
            float tzr = (float)d + sf * r * uz * cscale;
            float cx = fabsf(txr + 0.5f); float ix = fminf(cx, 96.0f - cx) - 0.5f;
            float cy = fabsf(tyr + 0.5f); float iy = fminf(cy, 96.0f - cy) - 0.5f;
            float cz = fabsf(tzr + 0.5f); float iz = fminf(cz, 96.0f - cz) - 0.5f;
            float x0f = floorf(ix), y0f = floorf(iy), z0f = floorf(iz);
            float fx = ix - x0f, fy = iy - y0f, fz = iz - z0f;
            int x0 = min(max((int)x0f, 0), 47); int x1 = min(x0 + 1, 47);
            int y0 = min(max((int)y0f, 0), 47); int y1 = min(y0 + 1, 47);
            int z0 = min(max((int)z0f, 0), 47); int z1 = min(z0 + 1, 47);
            float fxe = (x1 == x0) ? 0.0f : fx;  // reference's clipped-x1 semantics
            _Float16 hx = (_Float16)fxe, hy = (_Float16)fy, hz = (_Float16)fz;
            fx2[si] = (h2){hx, hx}; fy2[si] = (h2){hy, hy}; fz2[si] = (h2){hz, hz};
            int lz0 = z0 - zlo, lz1 = z1 - zlo;
            int ly0 = y0 - ylo, ly1 = y1 - ylo;
            int lx0 = x0 - xlo;
            a00[si] = (lz0 * 13 + ly0) * 13 + lx0;
            a01[si] = (lz0 * 13 + ly1) * 13 + lx0;
            a10[si] = (lz1 * 13 + ly0) * 13 + lx0;
            a11[si] = (lz1 * 13 + ly1) * 13 + lx0;
        }
    }

    // ---- stage group 0 tile into buffer 0 + zero both pad entries ----
    if (tid == 0) {
        q4 z; z.lo = (h2){0, 0}; z.hi = (h2){0, 0};
        tileq[TILE_N] = z; tileq[TILE_WSTR + TILE_N] = z;
    }
    {
        float ld[24];
#pragma unroll
        for (int cg = 0; cg < 4; ++cg) {
            const float* xc = xn + cg * DHW;
#pragma unroll
            for (int i = 0; i < 6; ++i) ld[cg * 6 + i] = xc[goff[i]];
        }
#pragma unroll
        for (int i = 0; i < 6; ++i) {
            int e = tid + i * 256;
            if (e < TILE_N) {
                q4 v; v.lo = pkrtz(ld[i], ld[6 + i]); v.hi = pkrtz(ld[12 + i], ld[18 + i]);
                tileq[e] = v;
            }
        }
    }
    __syncthreads();

    floatx4 acc[4][2];
#pragma unroll
    for (int mt = 0; mt < 4; ++mt)
#pragma unroll
        for (int nt = 0; nt < 2; ++nt) acc[mt][nt] = (floatx4){0.f, 0.f, 0.f, 0.f};

    const int self = ((lz + 2) * 13 + (ly + 2)) * 13 + (lx + 2);
    const unsigned short* bt = (const unsigned short*)(ws + WS_BT_F);
    const int tokq = (tid >> 3) & 3;           // token-quadrant swizzle key
    const int qm = lane >> 4, nlo = lane & 15;

    // B-fragment pipeline: group 0 loaded before the loop; in-loop we prefetch
    // g+1 at the top so the L2 latency hides under trilinear compute.
    short8 bc0 = *(const short8*)(bt + (nlo * 256 + qm * 8));
    short8 bc1 = *(const short8*)(bt + ((nlo + 16) * 256 + qm * 8));

    for (int g = 0; g < GROUPS; ++g) {
        const int rb = (g & 1);                // read buffer
        const int wb = rb ^ 1;                 // write buffer
        float nld[24];
        short8 bn0 = bc0, bn1 = bc1;
        if (g < GROUPS - 1) {
            const float* xg = xn + (g + 1) * 4 * DHW;
#pragma unroll
            for (int cg = 0; cg < 4; ++cg) {
                const float* xc = xg + cg * DHW;
#pragma unroll
                for (int i = 0; i < 6; ++i) nld[cg * 6 + i] = xc[goff[i]];
            }
            bn0 = *(const short8*)(bt + (nlo * 256 + (g + 1) * 32 + qm * 8));
            bn1 = *(const short8*)(bt + ((nlo + 16) * 256 + (g + 1) * 32 + qm * 8));
        }
        // ---- packed trilinear: all 4 channels per site (8B entries) ----
        const q4* tb = tileq + rb * TILE_WSTR;
        q4 s2 = tb[self];
        q4 vv[6];
#pragma unroll
        for (int si = 0; si < 6; ++si) {
            int b00 = a00[si], b01 = a01[si], b10 = a10[si], b11 = a11[si];
            q4 v000 = tb[b00], v001 = tb[b00 + 1];
            q4 v010 = tb[b01], v011 = tb[b01 + 1];
            q4 v100 = tb[b10], v101 = tb[b10 + 1];
            q4 v110 = tb[b11], v111 = tb[b11 + 1];
            h2 fx = fx2[si], fy = fy2[si], fz = fz2[si];
            h2 c00l = v000.lo + fx * (v001.lo - v000.lo);
            h2 c00h = v000.hi + fx * (v001.hi - v000.hi);
            h2 c01l = v010.lo + fx * (v011.lo - v010.lo);
            h2 c01h = v010.hi + fx * (v011.hi - v010.hi);
            h2 c10l = v100.lo + fx * (v101.lo - v100.lo);
            h2 c10h = v100.hi + fx * (v101.hi - v100.hi);
            h2 c11l = v110.lo + fx * (v111.lo - v110.lo);
            h2 c11h = v110.hi + fx * (v111.hi - v110.hi);
            h2 c0l = c00l + fy * (c01l - c00l);
            h2 c0h = c00h + fy * (c01h - c00h);
            h2 c1l = c10l + fy * (c11l - c10l);
            h2 c1h = c10h + fy * (c11h - c10h);
            vv[si].lo = c0l + fz * (c1l - c0l);
            vv[si].hi = c0h + fz * (c1h - c0h);
        }
        // ---- per-channel token assembly (fp32 math, fp16 pack) ----
#pragma unroll
        for (int sub = 0; sub < 4; ++sub) {
            float xv = (sub == 0) ? (float)s2.lo.x : (sub == 1) ? (float)s2.lo.y
                     : (sub == 2) ? (float)s2.hi.x : (float)s2.hi.y;
            float val[6];
#pragma unroll
            for (int si = 0; si < 6; ++si)
                val[si] = (sub == 0) ? (float)vv[si].lo.x : (sub == 1) ? (float)vv[si].lo.y
                        : (sub == 2) ? (float)vv[si].hi.x : (float)vv[si].hi.y;
            float t1, t2, t3, gx, gy, gz, l;
            {
                float sp, sm, d1;
                sp = val[0]; sm = val[1]; t1 = 0.5f * (sp + sm);
                d1 = 0.5f * (sp - sm) * irk[0];
                gx = uxk[0] * d1; gy = uyk[0] * d1; gz = uzk[0] * d1;
                l  = (sp + sm - 2.0f * xv) * ir2k[0];
                sp = val[2]; sm = val[3]; t2 = 0.5f * (sp + sm);
                d1 = 0.5f * (sp - sm) * irk[1];
                gx = fmaf(uxk[1], d1, gx); gy = fmaf(uyk[1], d1, gy); gz = fmaf(uzk[1], d1, gz);
                l  = fmaf(sp + sm - 2.0f * xv, ir2k[1], l);
                sp = val[4]; sm = val[5]; t3 = 0.5f * (sp + sm);
                d1 = 0.5f * (sp - sm) * irk[2];
                gx = fmaf(uxk[2], d1, gx); gy = fmaf(uyk[2], d1, gy); gz = fmaf(uzk[2], d1, gz);
                l  = fmaf(sp + sm - 2.0f * xv, ir2k[2], l);
            }
            uint4 tw;
            tw.x = pkrtz_u(xv, t1);
            tw.y = pkrtz_u(t2, t3);
            tw.z = pkrtz_u(gx, gy);
            tw.w = pkrtz_u(gz, l * (1.0f / 3.0f));
            int qe = sub ^ tokq;               // bank-conflict-free token write
            *(uint4*)(tokb + tid * TOK_STR + qe * 16) = tw;
        }
        // ---- MFMA: K-chunk g (k = g*32 .. g*32+31), fp16 ----
        // Tokens are wave-private: lgkmcnt (compiler-inserted) suffices, no barrier.
        {
            half8 hb0 = __builtin_bit_cast(half8, bc0);
            half8 hb1 = __builtin_bit_cast(half8, bc1);
#pragma unroll
            for (int mt = 0; mt < 4; ++mt) {
                int row = w64 + mt * 16 + nlo;
                int qe  = qm ^ ((row >> 3) & 3);
                half8 a = __builtin_bit_cast(half8,
                          *(const short8*)(tokb + row * TOK_STR + qe * 16));
                acc[mt][0] = __builtin_amdgcn_mfma_f32_16x16x32_f16(a, hb0, acc[mt][0], 0, 0, 0);
                acc[mt][1] = __builtin_amdgcn_mfma_f32_16x16x32_f16(a, hb1, acc[mt][1], 0, 0, 0);
            }
        }
        bc0 = bn0; bc1 = bn1;

        // ---- stage g+1 into the other tile buffer (vmcnt covered by above) ----
        if (g < GROUPS - 1) {
#pragma unroll
            for (int i = 0; i < 6; ++i) {
                int e = tid + i * 256;
                if (e < TILE_N) {
                    q4 v; v.lo = pkrtz(nld[i], nld[6 + i]); v.hi = pkrtz(nld[12 + i], nld[18 + i]);
                    tileq[wb * TILE_WSTR + e] = v;
                }
            }
        }
        __syncthreads();   // single rendezvous: buf^1 staged, buf reads done
    }

    // ---- C writeback via LDS (col-swizzled, conflict-free) ----
    {
#pragma unroll
        for (int mt = 0; mt < 4; ++mt)
#pragma unroll
            for (int nt = 0; nt < 2; ++nt)
#pragma unroll
                for (int r = 0; r < 4; ++r) {
                    int v = w64 + mt * 16 + qm * 4 + r;
                    int col = nt * 16 + nlo;
                    cbuf[v * 36 + (col ^ (v & 31))] = acc[mt][nt][r];
                }
    }
    __syncthreads();

    // ---- epilogue: out = x + delta + b_mix (coalesced, nontemporal) ----
    const float* dr = cbuf + tid * 36;
    float* on = out + (size_t)n * CH * DHW;
#pragma unroll
    for (int o = 0; o < 32; ++o)
        __builtin_nontemporal_store(
            xn[o * DHW + pos] + dr[o ^ (tid & 31)] + ws[WS_BM + o],
            on + o * DHW + pos);
}

extern "C" void kernel_launch(void* const* d_in, const int* in_sizes, int n_in,
                              void* d_out, int out_size, void* d_ws, size_t ws_size,
                              hipStream_t stream) {
    const float *x = (const float*)d_in[0], *w_field = (const float*)d_in[1],
                *b_field = (const float*)d_in[2], *gates = (const float*)d_in[3],
                *w_mix = (const float*)d_in[4], *b_mix = (const float*)d_in[5];
    for (int i = 0; i < n_in; ++i) {
        switch (in_sizes[i]) {
            case NB * CH * DHW: x       = (const float*)d_in[i]; break;
            case 12 * CH:       w_field = (const float*)d_in[i]; break;
            case 12:            b_field = (const float*)d_in[i]; break;
            case TT:            gates   = (const float*)d_in[i]; break;
            case CH * TT * CH:  w_mix   = (const float*)d_in[i]; break;
            case CH:            b_mix   = (const float*)d_in[i]; break;
            default: break;
        }
    }
    float* ws = (float*)d_ws;
    prep_kernel<<<32, 256, 0, stream>>>(w_field, b_field, gates, w_mix, b_mix, ws);
    geo_main<<<864, 256, 0, stream>>>(x, ws, (float*)d_out);
}